// Round 4
// baseline (835.831 us; speedup 1.0000x reference)
//
#include <hip/hip_runtime.h>

typedef __attribute__((ext_vector_type(8))) short short8;
typedef __attribute__((ext_vector_type(4))) float f32x4;

#define N_NODES 1000000
#define N_UPD   200000
#define D       172
#define BM      64          // rows per GRU block
#define LDA     360         // LDS A row stride in ushorts (720B -> 2-way banks)
#define KSTEPS  11          // 11 * 32 = 352 >= 344
#define NTILES  48          // 768 padded N cols / 16
#define GRU_BLOCKS (N_UPD / BM)              // 3125
#define NM4 43000000                         // N_NODES*D/4 float4s
#define BPACK_USHORTS (KSTEPS*NTILES*64*8)   // 270336
#define BIAS_OFF  (BPACK_USHORTS*2)          // 540672 B
#define MASK_OFF  (BIAS_OFF + 688*4)         // 543424 B (16B aligned)
#define WS_NEED   (MASK_OFF + N_NODES)       // ~1.55 MB

__device__ __forceinline__ unsigned short f2bf(float f) {
  union { float f; unsigned u; } v; v.f = f;
  unsigned r = v.u + 0x7FFFu + ((v.u >> 16) & 1u);
  return (unsigned short)(r >> 16);
}
__device__ __forceinline__ float bf2f(unsigned short h) {
  union { unsigned u; float f; } v; v.u = ((unsigned)h) << 16;
  return v.f;
}

// ---------------------------------------------------------------------------
// Prep: pack B into MFMA-fragment order + fused biases + clear node mask.
// Bpack[((ks*48+nt)*64+lane)*8+e] = B[ks*32+(lane>>4)*8+e][nt*16+(lane&15)]
// col group w=nt/12 owns cols w*48..w*48+48 of [r_pre|z_pre|i_n|h_n].
// ---------------------------------------------------------------------------
__global__ void prep_kernel(const float* __restrict__ wih, const float* __restrict__ whh,
                            const float* __restrict__ bih, const float* __restrict__ bhh,
                            unsigned short* __restrict__ Bpack, float* __restrict__ bias4,
                            uint4* __restrict__ mask16) {
  int gid = blockIdx.x * 256 + threadIdx.x;
  if (gid < 688) {
    int which = gid / 172, j = gid % 172;
    float v;
    if (which == 0)      v = bih[j]       + bhh[j];        // r
    else if (which == 1) v = bih[172 + j] + bhh[172 + j];  // z
    else if (which == 2) v = bih[344 + j];                 // i_n
    else                 v = bhh[344 + j];                 // h_n
    bias4[gid] = v;
  }
  if (gid < N_NODES / 16) mask16[gid] = make_uint4(0, 0, 0, 0);
  if (gid >= BPACK_USHORTS) return;
  int e  = gid & 7;
  int l  = (gid >> 3) & 63;
  int nt = (gid >> 9) % NTILES;
  int ks = gid / (512 * NTILES);
  int k  = ks * 32 + ((l >> 4) << 3) + e;
  int c  = l & 15;
  int w  = nt / 12, tl = nt % 12;
  int gate = tl / 3, ti = tl % 3;
  int j = w * 48 + ti * 16 + c;
  float v = 0.f;
  if (j < D) {
    if (gate == 0) {            // r_pre
      if (k < D)        v = wih[j * D + k];
      else if (k < 2*D) v = whh[j * D + (k - D)];
    } else if (gate == 1) {     // z_pre
      if (k < D)        v = wih[(D + j) * D + k];
      else if (k < 2*D) v = whh[(D + j) * D + (k - D)];
    } else if (gate == 2) {     // i_n
      if (k < D)        v = wih[(2*D + j) * D + k];
    } else {                    // h_n
      if (k >= D && k < 2*D) v = whh[(2*D + j) * D + (k - D)];
    }
  }
  Bpack[gid] = f2bf(v);
}

__global__ void mask_set_kernel(const int* __restrict__ ids, unsigned char* __restrict__ mask) {
  int i = blockIdx.x * 256 + threadIdx.x;
  if (i < N_UPD) mask[ids[i]] = 1;
}

// Full copy (fallback when ws too small for the mask)
__global__ void copy_kernel(const float4* __restrict__ mem4, const float4* __restrict__ lu4,
                            float4* __restrict__ out4, float4* __restrict__ outlu4) {
  const long NL4 = N_NODES / 4;
  long stride = (long)gridDim.x * blockDim.x;
  for (long i = (long)blockIdx.x * blockDim.x + threadIdx.x; i < NM4 + NL4; i += stride) {
    if (i < NM4) out4[i] = mem4[i];
    else         outlu4[i - NM4] = lu4[i - NM4];
  }
}

// Masked copy: skip rows the GRU kernel writes. High occupancy, no LDS.
__global__ __launch_bounds__(256)
void copy_masked_kernel(const float4* __restrict__ mem4, const float* __restrict__ lu,
                        const unsigned char* __restrict__ mask,
                        float4* __restrict__ out4, float* __restrict__ outlu) {
  const unsigned stride = gridDim.x * 256;
  for (unsigned i = blockIdx.x * 256 + threadIdx.x; i < NM4; i += stride) {
    unsigned row = i / 43u;
    if (!mask[row]) out4[i] = mem4[i];
  }
  for (unsigned j = blockIdx.x * 256 + threadIdx.x; j < N_NODES; j += stride) {
    if (!mask[j]) outlu[j] = lu[j];
  }
}

// ---------------------------------------------------------------------------
// GRU: 64 rows/block, 8 waves = 2 m-groups x 4 col-groups, 2 m-tiles/wave,
// 24 named f32x4 accumulators (no runtime-indexed arrays -> no scratch).
// ---------------------------------------------------------------------------
__global__ __launch_bounds__(512, 3)
void gru64_kernel(const float* __restrict__ memory, const float* __restrict__ msgs,
                  const int* __restrict__ ids, const float* __restrict__ ts,
                  const unsigned short* __restrict__ Bpack, const float* __restrict__ bias4,
                  float* __restrict__ out_mem, float* __restrict__ out_lu) {
  __shared__ unsigned short At[BM * LDA];
  __shared__ int ids_s[BM];
  const int tid = threadIdx.x;
  const int m0  = blockIdx.x * BM;

  if (tid < BM) {
    int nid = ids[m0 + tid];
    ids_s[tid] = nid;
    out_lu[nid] = ts[m0 + tid];
  }
  __syncthreads();

  // Stage A: per row, 43 float4 of x then 43 float4 of gathered h -> bf16
  for (int s = tid; s < BM * 86; s += 512) {
    int row = s / 86, seg = s % 86;
    float4 v; int kk;
    if (seg < 43) {
      v = ((const float4*)(msgs + (size_t)(m0 + row) * D))[seg];
      kk = seg * 4;
    } else {
      int s2 = seg - 43;
      v = ((const float4*)(memory + (size_t)ids_s[row] * D))[s2];
      kk = D + s2 * 4;
    }
    *(ushort4*)&At[row * LDA + kk] = make_ushort4(f2bf(v.x), f2bf(v.y), f2bf(v.z), f2bf(v.w));
  }
  if (tid < BM * 2) {   // zero-pad k = 344..359
    int row = tid >> 1, p = tid & 1;
    *(uint4*)&At[row * LDA + 2*D + p * 8] = make_uint4(0, 0, 0, 0);
  }
  __syncthreads();

  const int wave = tid >> 6, lane = tid & 63;
  const int g = lane >> 4, c = lane & 15;
  const int wm = wave >> 2, wc = wave & 3;   // m-group (32 rows), column group

  f32x4 C0_0={0,0,0,0}, C0_1={0,0,0,0}, C0_2={0,0,0,0}, C0_3={0,0,0,0};
  f32x4 C0_4={0,0,0,0}, C0_5={0,0,0,0}, C0_6={0,0,0,0}, C0_7={0,0,0,0};
  f32x4 C0_8={0,0,0,0}, C0_9={0,0,0,0}, C0_10={0,0,0,0}, C0_11={0,0,0,0};
  f32x4 C1_0={0,0,0,0}, C1_1={0,0,0,0}, C1_2={0,0,0,0}, C1_3={0,0,0,0};
  f32x4 C1_4={0,0,0,0}, C1_5={0,0,0,0}, C1_6={0,0,0,0}, C1_7={0,0,0,0};
  f32x4 C1_8={0,0,0,0}, C1_9={0,0,0,0}, C1_10={0,0,0,0}, C1_11={0,0,0,0};

  const short8* Bp = (const short8*)Bpack;
  const int ar0 = (wm * 32 + c) * LDA;
  const int ar1 = (wm * 32 + 16 + c) * LDA;

#define MMSTEP(NT) { short8 b = bb[(NT)*64]; \
    C0_##NT = __builtin_amdgcn_mfma_f32_16x16x32_bf16(a0, b, C0_##NT, 0, 0, 0); \
    C1_##NT = __builtin_amdgcn_mfma_f32_16x16x32_bf16(a1, b, C1_##NT, 0, 0, 0); }
  #pragma unroll 2
  for (int ks = 0; ks < KSTEPS; ++ks) {
    short8 a0 = *(const short8*)&At[ar0 + ks * 32 + g * 8];
    short8 a1 = *(const short8*)&At[ar1 + ks * 32 + g * 8];
    const short8* bb = Bp + (size_t)((ks * NTILES + wc * 12) * 64 + lane);
    MMSTEP(0)  MMSTEP(1)  MMSTEP(2)  MMSTEP(3)
    MMSTEP(4)  MMSTEP(5)  MMSTEP(6)  MMSTEP(7)
    MMSTEP(8)  MMSTEP(9)  MMSTEP(10) MMSTEP(11)
  }
#undef MMSTEP

#define DO_TI(TI, CR, CZ, CI, CH) { int j = wc * 48 + (TI) * 16 + c; if (j < D) { \
      float rp = CR[r] + bias4[j];        float zp = CZ[r] + bias4[172 + j];      \
      float ip = CI[r] + bias4[344 + j];  float hp = CH[r] + bias4[516 + j];      \
      float ho = bf2f(hrow[j]);                                                   \
      float rr = 1.f / (1.f + __expf(-rp));                                       \
      float zz = 1.f / (1.f + __expf(-zp));                                       \
      float e2 = __expf(2.f * (ip + rr * hp));                                    \
      float nn = 1.f - 2.f / (e2 + 1.f);                                          \
      orow[j] = nn + zz * (ho - nn); } }
  #pragma unroll
  for (int r = 0; r < 4; ++r) {
    {
      const int row_local = wm * 32 + g * 4 + r;            // m-tile 0
      float* orow = out_mem + (size_t)ids_s[row_local] * D;
      const unsigned short* hrow = &At[row_local * LDA + D];
      DO_TI(0, C0_0, C0_3, C0_6, C0_9)
      DO_TI(1, C0_1, C0_4, C0_7, C0_10)
      DO_TI(2, C0_2, C0_5, C0_8, C0_11)
    }
    {
      const int row_local = wm * 32 + 16 + g * 4 + r;       // m-tile 1
      float* orow = out_mem + (size_t)ids_s[row_local] * D;
      const unsigned short* hrow = &At[row_local * LDA + D];
      DO_TI(0, C1_0, C1_3, C1_6, C1_9)
      DO_TI(1, C1_1, C1_4, C1_7, C1_10)
      DO_TI(2, C1_2, C1_5, C1_8, C1_11)
    }
  }
#undef DO_TI
}

extern "C" void kernel_launch(void* const* d_in, const int* in_sizes, int n_in,
                              void* d_out, int out_size, void* d_ws, size_t ws_size,
                              hipStream_t stream) {
  const float* memory      = (const float*)d_in[0];
  const float* last_update = (const float*)d_in[1];
  const int*   ids         = (const int*)  d_in[2];
  const float* msgs        = (const float*)d_in[3];
  const float* ts          = (const float*)d_in[4];
  const float* wih         = (const float*)d_in[5];
  const float* whh         = (const float*)d_in[6];
  const float* bih         = (const float*)d_in[7];
  const float* bhh         = (const float*)d_in[8];

  float* out_mem = (float*)d_out;
  float* out_lu  = out_mem + (size_t)N_NODES * D;

  unsigned short* Bpack = (unsigned short*)d_ws;
  float* bias4 = (float*)((char*)d_ws + BIAS_OFF);
  unsigned char* mask = (unsigned char*)d_ws + MASK_OFF;

  prep_kernel<<<BPACK_USHORTS / 256, 256, 0, stream>>>(wih, whh, bih, bhh, Bpack, bias4,
                                                       (uint4*)mask);
  if (ws_size >= WS_NEED) {
    mask_set_kernel<<<(N_UPD + 255) / 256, 256, 0, stream>>>(ids, mask);
    copy_masked_kernel<<<2048, 256, 0, stream>>>((const float4*)memory, last_update, mask,
                                                 (float4*)out_mem, out_lu);
  } else {
    copy_kernel<<<4096, 256, 0, stream>>>((const float4*)memory, (const float4*)last_update,
                                          (float4*)out_mem, (float4*)out_lu);
  }
  gru64_kernel<<<GRU_BLOCKS, 512, 0, stream>>>(memory, msgs, ids, ts, Bpack, bias4,
                                               out_mem, out_lu);
}

// Round 6
// 589.286 us; speedup vs baseline: 1.4184x; 1.4184x over previous
//
#include <hip/hip_runtime.h>

typedef __attribute__((ext_vector_type(8))) short short8;
typedef __attribute__((ext_vector_type(4))) float f32x4;

#define N_NODES 1000000
#define N_UPD   200000
#define D       172
#define BM      64          // rows per GRU block
#define LDA     360         // LDS A row stride in ushorts (720B -> 2-way-free banks)
#define KSTEPS  11          // 11 * 32 = 352 >= 344
#define NTILES  48          // 768 padded N cols / 16
#define KSLICE  (NTILES*512)                 // ushorts per ks B slice (24576 = 48KB)
#define GRU_BLOCKS (N_UPD / BM)              // 3125
#define NM4 43000000                         // N_NODES*D/4 float4s
#define BPACK_USHORTS (KSTEPS*KSLICE)        // 270336
#define BIAS_OFF  (BPACK_USHORTS*2)          // 540672 B
#define MASK_OFF  (BIAS_OFF + 688*4)         // 543424 B (16B aligned)
#define WS_NEED   (MASK_OFF + N_NODES)       // ~1.55 MB

__device__ __forceinline__ unsigned short f2bf(float f) {
  union { float f; unsigned u; } v; v.f = f;
  unsigned r = v.u + 0x7FFFu + ((v.u >> 16) & 1u);
  return (unsigned short)(r >> 16);
}
__device__ __forceinline__ float bf2f(unsigned short h) {
  union { unsigned u; float f; } v; v.u = ((unsigned)h) << 16;
  return v.f;
}
__device__ __forceinline__ ushort4 f2bf4(float4 v) {
  return make_ushort4(f2bf(v.x), f2bf(v.y), f2bf(v.z), f2bf(v.w));
}

// async global->LDS, 16B per lane (dest = wave-uniform base + lane*16)
__device__ __forceinline__ void gld16(const unsigned short* g, unsigned short* l) {
  __builtin_amdgcn_global_load_lds(
      (const __attribute__((address_space(1))) unsigned int*)g,
      (__attribute__((address_space(3))) unsigned int*)l, 16, 0, 0);
}

// ---------------------------------------------------------------------------
// Prep: pack B into MFMA-fragment order + fused biases + clear node mask.
// Bpack[((ks*48+nt)*64+lane)*8+e] = B[ks*32+(lane>>4)*8+e][nt*16+(lane&15)]
// col group w=nt/12 owns cols w*48..w*48+48 of [r_pre|z_pre|i_n|h_n].
// ---------------------------------------------------------------------------
__global__ void prep_kernel(const float* __restrict__ wih, const float* __restrict__ whh,
                            const float* __restrict__ bih, const float* __restrict__ bhh,
                            unsigned short* __restrict__ Bpack, float* __restrict__ bias4,
                            uint4* __restrict__ mask16) {
  int gid = blockIdx.x * 256 + threadIdx.x;
  if (gid < 688) {
    int which = gid / 172, j = gid % 172;
    float v;
    if (which == 0)      v = bih[j]       + bhh[j];        // r
    else if (which == 1) v = bih[172 + j] + bhh[172 + j];  // z
    else if (which == 2) v = bih[344 + j];                 // i_n
    else                 v = bhh[344 + j];                 // h_n
    bias4[gid] = v;
  }
  if (gid < N_NODES / 16) mask16[gid] = make_uint4(0, 0, 0, 0);
  if (gid >= BPACK_USHORTS) return;
  int e  = gid & 7;
  int l  = (gid >> 3) & 63;
  int nt = (gid >> 9) % NTILES;
  int ks = gid / KSLICE;
  int k  = ks * 32 + ((l >> 4) << 3) + e;
  int c  = l & 15;
  int w  = nt / 12, tl = nt % 12;
  int gate = tl / 3, ti = tl % 3;
  int j = w * 48 + ti * 16 + c;
  float v = 0.f;
  if (j < D) {
    if (gate == 0) {            // r_pre
      if (k < D)        v = wih[j * D + k];
      else if (k < 2*D) v = whh[j * D + (k - D)];
    } else if (gate == 1) {     // z_pre
      if (k < D)        v = wih[(D + j) * D + k];
      else if (k < 2*D) v = whh[(D + j) * D + (k - D)];
    } else if (gate == 2) {     // i_n
      if (k < D)        v = wih[(2*D + j) * D + k];
    } else {                    // h_n
      if (k >= D && k < 2*D) v = whh[(2*D + j) * D + (k - D)];
    }
  }
  Bpack[gid] = f2bf(v);
}

__global__ void mask_set_kernel(const int* __restrict__ ids, unsigned char* __restrict__ mask) {
  int i = blockIdx.x * 256 + threadIdx.x;
  if (i < N_UPD) mask[ids[i]] = 1;
}

// Full copy (fallback when ws too small for the mask)
__global__ void copy_kernel(const float4* __restrict__ mem4, const float4* __restrict__ lu4,
                            float4* __restrict__ out4, float4* __restrict__ outlu4) {
  const long NL4 = N_NODES / 4;
  long stride = (long)gridDim.x * blockDim.x;
  for (long i = (long)blockIdx.x * blockDim.x + threadIdx.x; i < NM4 + NL4; i += stride) {
    if (i < NM4) out4[i] = mem4[i];
    else         outlu4[i - NM4] = lu4[i - NM4];
  }
}

// Masked copy: skip rows the GRU kernel writes. High occupancy, no LDS.
__global__ __launch_bounds__(256)
void copy_masked_kernel(const float4* __restrict__ mem4, const float* __restrict__ lu,
                        const unsigned char* __restrict__ mask,
                        float4* __restrict__ out4, float* __restrict__ outlu) {
  const unsigned stride = gridDim.x * 256;
  for (unsigned i = blockIdx.x * 256 + threadIdx.x; i < NM4; i += stride) {
    unsigned row = i / 43u;
    if (!mask[row]) out4[i] = mem4[i];
  }
  for (unsigned j = blockIdx.x * 256 + threadIdx.x; j < N_NODES; j += stride) {
    if (!mask[j]) outlu[j] = lu[j];
  }
}

// ---------------------------------------------------------------------------
// GRU: 64 rows/block, 8 waves = 2 m-groups x 4 col-groups.
// B double-buffered in LDS via global_load_lds (48KB/ks slice, contiguous).
// A staged with compile-time-unrolled loads (12 in flight per thread).
// ---------------------------------------------------------------------------
__global__ __launch_bounds__(512, 2)
void gru64_kernel(const float* __restrict__ memory, const float* __restrict__ msgs,
                  const int* __restrict__ ids, const float* __restrict__ ts,
                  const unsigned short* __restrict__ Bpack, const float* __restrict__ bias4,
                  float* __restrict__ out_mem, float* __restrict__ out_lu) {
  __shared__ unsigned short At[BM * LDA];       // 46080 B
  __shared__ unsigned short Bl[2][KSLICE];      // 98304 B
  const int tid  = threadIdx.x;
  const int m0   = blockIdx.x * BM;
  const int wave = tid >> 6, lane = tid & 63;
  const int g = lane >> 4, c = lane & 15;
  const int wm = wave >> 2, wc = wave & 3;

  // prefetch B[ks=0] first: its L2 latency overlaps the HBM staging below
  {
    const unsigned short* src = Bpack;
    #pragma unroll
    for (int i = 0; i < 6; ++i) {
      int off = (wave * 6 + i) * 512 + lane * 8;
      gld16(src + off, &Bl[0][0] + off);
    }
  }

  // ---- A staging: 2752 x-slots + 2752 h-slots of 16B, 6+6 per thread ----
  const float4* x4 = (const float4*)msgs + (size_t)m0 * 43;
  float4 xv[6], hv[6];
  #pragma unroll
  for (int i = 0; i < 6; ++i) {
    int s = tid + i * 512;
    if (i < 5 || s < 2752) xv[i] = x4[s];
  }
  #pragma unroll
  for (int i = 0; i < 6; ++i) {
    int s = tid + i * 512;
    if (i < 5 || s < 2752) {
      int row = s / 43, seg = s - row * 43;
      int nid = ids[m0 + row];
      hv[i] = ((const float4*)(memory + (size_t)nid * D))[seg];
    }
  }
  #pragma unroll
  for (int i = 0; i < 6; ++i) {
    int s = tid + i * 512;
    if (i < 5 || s < 2752) {
      int row = s / 43, seg = s - row * 43;
      *(ushort4*)&At[row * LDA + seg * 4]       = f2bf4(xv[i]);
      *(ushort4*)&At[row * LDA + 172 + seg * 4] = f2bf4(hv[i]);
    }
  }
  if (tid < BM) {   // zero-pad k=344..351 + last_update scatter
    *(uint4*)&At[tid * LDA + 344] = make_uint4(0, 0, 0, 0);
    int nid = ids[m0 + tid];
    out_lu[nid] = ts[m0 + tid];
  }
  __syncthreads();   // drains vmcnt: A staged AND B[0] landed

  f32x4 C0_0={0,0,0,0}, C0_1={0,0,0,0}, C0_2={0,0,0,0}, C0_3={0,0,0,0};
  f32x4 C0_4={0,0,0,0}, C0_5={0,0,0,0}, C0_6={0,0,0,0}, C0_7={0,0,0,0};
  f32x4 C0_8={0,0,0,0}, C0_9={0,0,0,0}, C0_10={0,0,0,0}, C0_11={0,0,0,0};
  f32x4 C1_0={0,0,0,0}, C1_1={0,0,0,0}, C1_2={0,0,0,0}, C1_3={0,0,0,0};
  f32x4 C1_4={0,0,0,0}, C1_5={0,0,0,0}, C1_6={0,0,0,0}, C1_7={0,0,0,0};
  f32x4 C1_8={0,0,0,0}, C1_9={0,0,0,0}, C1_10={0,0,0,0}, C1_11={0,0,0,0};

  const int ar0 = (wm * 32 + c) * LDA;
  const int ar1 = (wm * 32 + 16 + c) * LDA;

#define MMSTEP(NT) { short8 b = bb[(NT)*64]; \
    C0_##NT = __builtin_amdgcn_mfma_f32_16x16x32_bf16(a0, b, C0_##NT, 0, 0, 0); \
    C1_##NT = __builtin_amdgcn_mfma_f32_16x16x32_bf16(a1, b, C1_##NT, 0, 0, 0); }
  int cur = 0;
  #pragma unroll 1
  for (int ks = 0; ks < KSTEPS; ++ks) {
    if (ks + 1 < KSTEPS) {   // prefetch next slice into the other buffer
      const unsigned short* src = Bpack + (size_t)(ks + 1) * KSLICE;
      unsigned short* dst = &Bl[cur ^ 1][0];
      #pragma unroll
      for (int i = 0; i < 6; ++i) {
        int off = (wave * 6 + i) * 512 + lane * 8;
        gld16(src + off, dst + off);
      }
    }
    short8 a0 = *(const short8*)&At[ar0 + ks * 32 + g * 8];
    short8 a1 = *(const short8*)&At[ar1 + ks * 32 + g * 8];
    const short8* bb = (const short8*)&Bl[cur][wc * 12 * 512 + lane * 8];
    MMSTEP(0)  MMSTEP(1)  MMSTEP(2)  MMSTEP(3)
    MMSTEP(4)  MMSTEP(5)  MMSTEP(6)  MMSTEP(7)
    MMSTEP(8)  MMSTEP(9)  MMSTEP(10) MMSTEP(11)
    __syncthreads();   // all waves done reading Bl[cur]; prefetch landed
    cur ^= 1;
  }
#undef MMSTEP

#define DO_TI(TI, CR, CZ, CI, CH) { int j = wc * 48 + (TI) * 16 + c; if (j < D) { \
      float rp = CR[r] + bias4[j];        float zp = CZ[r] + bias4[172 + j];      \
      float ip = CI[r] + bias4[344 + j];  float hp = CH[r] + bias4[516 + j];      \
      float ho = bf2f(hrow[j]);                                                   \
      float rr = 1.f / (1.f + __expf(-rp));                                       \
      float zz = 1.f / (1.f + __expf(-zp));                                       \
      float e2 = __expf(2.f * (ip + rr * hp));                                    \
      float nn = 1.f - 2.f / (e2 + 1.f);                                          \
      orow[j] = nn + zz * (ho - nn); } }
  #pragma unroll
  for (int r = 0; r < 4; ++r) {
    {
      const int row_local = wm * 32 + g * 4 + r;            // m-tile 0
      float* orow = out_mem + (size_t)ids[m0 + row_local] * D;
      const unsigned short* hrow = &At[row_local * LDA + 172];
      DO_TI(0, C0_0, C0_3, C0_6, C0_9)
      DO_TI(1, C0_1, C0_4, C0_7, C0_10)
      DO_TI(2, C0_2, C0_5, C0_8, C0_11)
    }
    {
      const int row_local = wm * 32 + 16 + g * 4 + r;       // m-tile 1
      float* orow = out_mem + (size_t)ids[m0 + row_local] * D;
      const unsigned short* hrow = &At[row_local * LDA + 172];
      DO_TI(0, C1_0, C1_3, C1_6, C1_9)
      DO_TI(1, C1_1, C1_4, C1_7, C1_10)
      DO_TI(2, C1_2, C1_5, C1_8, C1_11)
    }
  }
#undef DO_TI
}

extern "C" void kernel_launch(void* const* d_in, const int* in_sizes, int n_in,
                              void* d_out, int out_size, void* d_ws, size_t ws_size,
                              hipStream_t stream) {
  const float* memory      = (const float*)d_in[0];
  const float* last_update = (const float*)d_in[1];
  const int*   ids         = (const int*)  d_in[2];
  const float* msgs        = (const float*)d_in[3];
  const float* ts          = (const float*)d_in[4];
  const float* wih         = (const float*)d_in[5];
  const float* whh         = (const float*)d_in[6];
  const float* bih         = (const float*)d_in[7];
  const float* bhh         = (const float*)d_in[8];

  float* out_mem = (float*)d_out;
  float* out_lu  = out_mem + (size_t)N_NODES * D;

  unsigned short* Bpack = (unsigned short*)d_ws;
  float* bias4 = (float*)((char*)d_ws + BIAS_OFF);
  unsigned char* mask = (unsigned char*)d_ws + MASK_OFF;

  prep_kernel<<<BPACK_USHORTS / 256, 256, 0, stream>>>(wih, whh, bih, bhh, Bpack, bias4,
                                                       (uint4*)mask);
  if (ws_size >= WS_NEED) {
    mask_set_kernel<<<(N_UPD + 255) / 256, 256, 0, stream>>>(ids, mask);
    copy_masked_kernel<<<2048, 256, 0, stream>>>((const float4*)memory, last_update, mask,
                                                 (float4*)out_mem, out_lu);
  } else {
    copy_kernel<<<4096, 256, 0, stream>>>((const float4*)memory, (const float4*)last_update,
                                          (float4*)out_mem, (float4*)out_lu);
  }
  gru64_kernel<<<GRU_BLOCKS, 512, 0, stream>>>(memory, msgs, ids, ts, Bpack, bias4,
                                               out_mem, out_lu);
}

// Round 7
// 577.880 us; speedup vs baseline: 1.4464x; 1.0197x over previous
//
#include <hip/hip_runtime.h>

typedef __attribute__((ext_vector_type(8))) short short8;
typedef __attribute__((ext_vector_type(4))) float f32x4;

#define N_NODES 1000000
#define N_UPD   200000
#define D       172
#define BM      96          // rows per GRU block
#define THREADS 768         // 12 waves = 3 m-groups x 4 col-groups
#define LDA     360         // LDS A row stride in ushorts (720B -> 2-way-free banks)
#define KSTEPS  11          // 11 * 32 = 352 >= 344
#define NTILES  48
#define KSLICE  (NTILES*512)                 // 24576 ushorts = 48KB per ks slice
#define NGRU    2084                         // ceil(200000/96)
#define NGRU_G  261                          // ceil(NGRU/8)
#define NCOPY_G 512
#define NCOPY_BLOCKS 4096
#define COPY_THREADS (NCOPY_BLOCKS*THREADS)  // 3145728
#define NM4 43000000
#define BPACK_USHORTS (KSTEPS*KSLICE)        // 270336
#define BIAS_OFF  (BPACK_USHORTS*2)          // 540672 B
#define MASK_OFF  (BIAS_OFF + 688*4)         // 543424 B
#define WS_NEED   (MASK_OFF + N_NODES)

__device__ __forceinline__ unsigned short f2bf(float f) {
  union { float f; unsigned u; } v; v.f = f;
  unsigned r = v.u + 0x7FFFu + ((v.u >> 16) & 1u);
  return (unsigned short)(r >> 16);
}
__device__ __forceinline__ float bf2f(unsigned short h) {
  union { unsigned u; float f; } v; v.u = ((unsigned)h) << 16;
  return v.f;
}
__device__ __forceinline__ ushort4 f2bf4(float4 v) {
  return make_ushort4(f2bf(v.x), f2bf(v.y), f2bf(v.z), f2bf(v.w));
}
__device__ __forceinline__ void gld16(const unsigned short* g, unsigned short* l) {
  __builtin_amdgcn_global_load_lds(
      (const __attribute__((address_space(1))) unsigned int*)g,
      (__attribute__((address_space(3))) unsigned int*)l, 16, 0, 0);
}

// ---------------------------------------------------------------------------
// Prep: pack B into MFMA-fragment order + fused biases + clear node mask.
// ---------------------------------------------------------------------------
__global__ void prep_kernel(const float* __restrict__ wih, const float* __restrict__ whh,
                            const float* __restrict__ bih, const float* __restrict__ bhh,
                            unsigned short* __restrict__ Bpack, float* __restrict__ bias4,
                            uint4* __restrict__ mask16) {
  int gid = blockIdx.x * 256 + threadIdx.x;
  if (gid < 688) {
    int which = gid / 172, j = gid % 172;
    float v;
    if (which == 0)      v = bih[j]       + bhh[j];
    else if (which == 1) v = bih[172 + j] + bhh[172 + j];
    else if (which == 2) v = bih[344 + j];
    else                 v = bhh[344 + j];
    bias4[gid] = v;
  }
  if (gid < N_NODES / 16) mask16[gid] = make_uint4(0, 0, 0, 0);
  if (gid >= BPACK_USHORTS) return;
  int e  = gid & 7;
  int l  = (gid >> 3) & 63;
  int nt = (gid >> 9) % NTILES;
  int ks = gid / KSLICE;
  int k  = ks * 32 + ((l >> 4) << 3) + e;
  int c  = l & 15;
  int w  = nt / 12, tl = nt % 12;
  int gate = tl / 3, ti = tl % 3;
  int j = w * 48 + ti * 16 + c;
  float v = 0.f;
  if (j < D) {
    if (gate == 0) {
      if (k < D)        v = wih[j * D + k];
      else if (k < 2*D) v = whh[j * D + (k - D)];
    } else if (gate == 1) {
      if (k < D)        v = wih[(D + j) * D + k];
      else if (k < 2*D) v = whh[(D + j) * D + (k - D)];
    } else if (gate == 2) {
      if (k < D)        v = wih[(2*D + j) * D + k];
    } else {
      if (k >= D && k < 2*D) v = whh[(2*D + j) * D + (k - D)];
    }
  }
  Bpack[gid] = f2bf(v);
}

__global__ void mask_set_kernel(const int* __restrict__ ids, unsigned char* __restrict__ mask) {
  int i = blockIdx.x * 256 + threadIdx.x;
  if (i < N_UPD) mask[ids[i]] = 1;
}

// Full copy (fallback when ws too small for the mask)
__global__ void copy_kernel(const float4* __restrict__ mem4, const float4* __restrict__ lu4,
                            float4* __restrict__ out4, float4* __restrict__ outlu4) {
  const long NL4 = N_NODES / 4;
  long stride = (long)gridDim.x * blockDim.x;
  for (long i = (long)blockIdx.x * blockDim.x + threadIdx.x; i < NM4 + NL4; i += stride) {
    if (i < NM4) out4[i] = mem4[i];
    else         outlu4[i - NM4] = lu4[i - NM4];
  }
}

// ---------------------------------------------------------------------------
// Fused kernel. Block groups of 8 (XCD round-robin): per triple of groups,
// 1 gru group : 2 copy groups. Copy skips masked rows; gru writes them.
// GRU: 96 rows, 12 waves = 3 m-groups x 4 col-groups, 24 named accs/wave.
// B: single 48KB LDS buffer, async reg-staged (T14: load early, write late).
// ---------------------------------------------------------------------------
__global__ __launch_bounds__(THREADS, 3)
void fused_kernel(const float* __restrict__ memory, const float* __restrict__ last_update,
                  const float* __restrict__ msgs, const int* __restrict__ ids,
                  const float* __restrict__ ts, const unsigned short* __restrict__ Bpack,
                  const float* __restrict__ bias4, const unsigned char* __restrict__ mask,
                  float* __restrict__ out_mem, float* __restrict__ out_lu, int ncopyg) {
  __shared__ unsigned short At[BM * LDA];   // 69120 B
  __shared__ unsigned short Bl[KSLICE];     // 49152 B
  const int tid = threadIdx.x;
  const int g8 = blockIdx.x >> 3, b7 = blockIdx.x & 7;

  int sub; bool is_copy = false;
  if (ncopyg) {
    int r = g8 % 3, q = g8 / 3;
    if (r == 0) sub = q;
    else { is_copy = true; sub = q * 2 + (r - 1); if (sub >= NCOPY_G) return; }
  } else sub = g8;

  if (is_copy) {
    // ---- masked copy path ----
    const int cblk = sub * 8 + b7;
    const float4* mem4 = (const float4*)memory;
    float4* out4 = (float4*)out_mem;
    for (unsigned i = (unsigned)cblk * THREADS + tid; i < NM4; i += COPY_THREADS) {
      unsigned row = i / 43u;
      if (!mask[row]) out4[i] = mem4[i];
    }
    for (unsigned j = (unsigned)cblk * THREADS + tid; j < N_NODES; j += COPY_THREADS) {
      if (!mask[j]) out_lu[j] = last_update[j];
    }
    return;
  }

  // ---- GRU path ----
  const int idx = sub * 8 + b7;
  const int m0  = idx * BM;
  if (m0 >= N_UPD) return;
  const int wave = tid >> 6, lane = tid & 63;
  const int g = lane >> 4, c = lane & 15;
  const int wm = wave >> 2, wc = wave & 3;

  // prefetch B[ks=0] async -> LDS (latency overlaps A staging)
  #pragma unroll
  for (int i = 0; i < 4; ++i) {
    int off = (wave * 4 + i) * 512 + lane * 8;
    gld16(Bpack + off, &Bl[0] + off);
  }

  // A staging: 96 rows x (43 x-float4 + 43 h-float4), clamped for tail block
  const int vlim = min(BM * 43, (N_UPD - m0) * 43);
  const float4* x4 = (const float4*)msgs + (size_t)m0 * 43;
  float4 xv[6], hv[6];
  #pragma unroll
  for (int i = 0; i < 6; ++i) {
    int s = tid + i * THREADS; int sc = min(s, vlim - 1);
    xv[i] = x4[sc];
  }
  #pragma unroll
  for (int i = 0; i < 6; ++i) {
    int s = tid + i * THREADS; int sc = min(s, vlim - 1);
    int row = sc / 43, seg = sc - row * 43;
    hv[i] = ((const float4*)(memory + (size_t)ids[m0 + row] * D))[seg];
  }
  #pragma unroll
  for (int i = 0; i < 6; ++i) {
    int s = tid + i * THREADS; int sc = min(s, vlim - 1);
    int row = sc / 43, seg = sc - row * 43;
    *(ushort4*)&At[row * LDA + seg * 4]       = f2bf4(xv[i]);
    *(ushort4*)&At[row * LDA + 172 + seg * 4] = f2bf4(hv[i]);
  }
  if (tid < BM) {
    *(uint4*)&At[tid * LDA + 344] = make_uint4(0, 0, 0, 0);
    if (m0 + tid < N_UPD) out_lu[ids[m0 + tid]] = ts[m0 + tid];
  }
  __syncthreads();   // A staged, B[0] landed

  f32x4 C0_0={0,0,0,0}, C0_1={0,0,0,0}, C0_2={0,0,0,0}, C0_3={0,0,0,0};
  f32x4 C0_4={0,0,0,0}, C0_5={0,0,0,0}, C0_6={0,0,0,0}, C0_7={0,0,0,0};
  f32x4 C0_8={0,0,0,0}, C0_9={0,0,0,0}, C0_10={0,0,0,0}, C0_11={0,0,0,0};
  f32x4 C1_0={0,0,0,0}, C1_1={0,0,0,0}, C1_2={0,0,0,0}, C1_3={0,0,0,0};
  f32x4 C1_4={0,0,0,0}, C1_5={0,0,0,0}, C1_6={0,0,0,0}, C1_7={0,0,0,0};
  f32x4 C1_8={0,0,0,0}, C1_9={0,0,0,0}, C1_10={0,0,0,0}, C1_11={0,0,0,0};

  const int ar0 = (wm * 32 + c) * LDA;
  const int ar1 = ar0 + 16 * LDA;
  const int boff = (wave * 4) * 64 + lane;   // float4 units

#define MMSTEP(NT) { short8 b = bb[(NT)*64]; \
    C0_##NT = __builtin_amdgcn_mfma_f32_16x16x32_bf16(a0, b, C0_##NT, 0, 0, 0); \
    C1_##NT = __builtin_amdgcn_mfma_f32_16x16x32_bf16(a1, b, C1_##NT, 0, 0, 0); }
  #pragma unroll 1
  for (int ks = 0; ks < KSTEPS; ++ks) {
    float4 s0, s1, s2, s3;
    const bool pf = (ks + 1 < KSTEPS);
    if (pf) {   // issue next-slice loads EARLY; they land during the MFMAs
      const float4* bsrc = (const float4*)(Bpack + (size_t)(ks + 1) * KSLICE) + boff;
      s0 = bsrc[0]; s1 = bsrc[64]; s2 = bsrc[128]; s3 = bsrc[192];
    }
    short8 a0 = *(const short8*)&At[ar0 + ks * 32 + g * 8];
    short8 a1 = *(const short8*)&At[ar1 + ks * 32 + g * 8];
    const short8* bb = (const short8*)&Bl[wc * 6144 + lane * 8];
    MMSTEP(0)  MMSTEP(1)  MMSTEP(2)  MMSTEP(3)
    MMSTEP(4)  MMSTEP(5)  MMSTEP(6)  MMSTEP(7)
    MMSTEP(8)  MMSTEP(9)  MMSTEP(10) MMSTEP(11)
    if (pf) {
      __syncthreads();   // everyone done reading Bl[ks]
      float4* bdst = (float4*)Bl + boff;
      bdst[0] = s0; bdst[64] = s1; bdst[128] = s2; bdst[192] = s3;
      __syncthreads();   // Bl[ks+1] visible
    }
  }
#undef MMSTEP

#define DO_TI(TI, CR, CZ, CI, CH) { int j = wc * 48 + (TI) * 16 + c; if (j < D) { \
      float rp = CR[r] + bias4[j];        float zp = CZ[r] + bias4[172 + j];      \
      float ip = CI[r] + bias4[344 + j];  float hp = CH[r] + bias4[516 + j];      \
      float ho = bf2f(hrow[j]);                                                   \
      float rr = 1.f / (1.f + __expf(-rp));                                       \
      float zz = 1.f / (1.f + __expf(-zp));                                       \
      float e2 = __expf(2.f * (ip + rr * hp));                                    \
      float nn = 1.f - 2.f / (e2 + 1.f);                                          \
      orow[j] = nn + zz * (ho - nn); } }
  #pragma unroll
  for (int r = 0; r < 4; ++r) {
    {
      const int row_local = wm * 32 + g * 4 + r;
      if (m0 + row_local < N_UPD) {
        float* orow = out_mem + (size_t)ids[m0 + row_local] * D;
        const unsigned short* hrow = &At[row_local * LDA + 172];
        DO_TI(0, C0_0, C0_3, C0_6, C0_9)
        DO_TI(1, C0_1, C0_4, C0_7, C0_10)
        DO_TI(2, C0_2, C0_5, C0_8, C0_11)
      }
    }
    {
      const int row_local = wm * 32 + 16 + g * 4 + r;
      if (m0 + row_local < N_UPD) {
        float* orow = out_mem + (size_t)ids[m0 + row_local] * D;
        const unsigned short* hrow = &At[row_local * LDA + 172];
        DO_TI(0, C1_0, C1_3, C1_6, C1_9)
        DO_TI(1, C1_1, C1_4, C1_7, C1_10)
        DO_TI(2, C1_2, C1_5, C1_8, C1_11)
      }
    }
  }
#undef DO_TI
}

extern "C" void kernel_launch(void* const* d_in, const int* in_sizes, int n_in,
                              void* d_out, int out_size, void* d_ws, size_t ws_size,
                              hipStream_t stream) {
  const float* memory      = (const float*)d_in[0];
  const float* last_update = (const float*)d_in[1];
  const int*   ids         = (const int*)  d_in[2];
  const float* msgs        = (const float*)d_in[3];
  const float* ts          = (const float*)d_in[4];
  const float* wih         = (const float*)d_in[5];
  const float* whh         = (const float*)d_in[6];
  const float* bih         = (const float*)d_in[7];
  const float* bhh         = (const float*)d_in[8];

  float* out_mem = (float*)d_out;
  float* out_lu  = out_mem + (size_t)N_NODES * D;

  unsigned short* Bpack = (unsigned short*)d_ws;
  float* bias4 = (float*)((char*)d_ws + BIAS_OFF);
  unsigned char* mask = (unsigned char*)d_ws + MASK_OFF;

  prep_kernel<<<BPACK_USHORTS / 256, 256, 0, stream>>>(wih, whh, bih, bhh, Bpack, bias4,
                                                       (uint4*)mask);
  if (ws_size >= WS_NEED) {
    mask_set_kernel<<<(N_UPD + 255) / 256, 256, 0, stream>>>(ids, mask);
    fused_kernel<<<NGRU_G * 3 * 8, THREADS, 0, stream>>>(
        memory, last_update, msgs, ids, ts, Bpack, bias4, mask, out_mem, out_lu, NCOPY_G);
  } else {
    copy_kernel<<<4096, 256, 0, stream>>>((const float4*)memory, (const float4*)last_update,
                                          (float4*)out_mem, (float4*)out_lu);
    fused_kernel<<<NGRU_G * 8, THREADS, 0, stream>>>(
        memory, last_update, msgs, ids, ts, Bpack, bias4, mask, out_mem, out_lu, 0);
  }
}

// Round 8
// 492.676 us; speedup vs baseline: 1.6965x; 1.1729x over previous
//
#include <hip/hip_runtime.h>

typedef __attribute__((ext_vector_type(8))) short short8;
typedef __attribute__((ext_vector_type(4))) float f32x4;

#define N_NODES 1000000
#define N_UPD   200000
#define D       172
#define BM      64          // rows per GRU block
#define LDA     360         // LDS A row stride in ushorts
#define KSTEPS  11          // 11 * 32 = 352 >= 344
#define NTILES  48
#define KSLICE  (NTILES*512)
#define GRU_BLOCKS (N_UPD / BM)              // 3125
#define NM4 43000000
#define BPACK_USHORTS (KSTEPS*KSLICE)        // 270336
#define BIAS_OFF  (BPACK_USHORTS*2)          // 540672 B
#define MASK_OFF  (BIAS_OFF + 688*4)         // 543424 B
#define WS_NEED   (MASK_OFF + N_NODES)

__device__ __forceinline__ unsigned short f2bf(float f) {
  union { float f; unsigned u; } v; v.f = f;
  unsigned r = v.u + 0x7FFFu + ((v.u >> 16) & 1u);
  return (unsigned short)(r >> 16);
}
__device__ __forceinline__ float bf2f(unsigned short h) {
  union { unsigned u; float f; } v; v.u = ((unsigned)h) << 16;
  return v.f;
}
__device__ __forceinline__ ushort4 f2bf4(float4 v) {
  return make_ushort4(f2bf(v.x), f2bf(v.y), f2bf(v.z), f2bf(v.w));
}

// ---------------------------------------------------------------------------
// Prep: pack B into MFMA-fragment order + fused biases + clear node mask.
// Bpack[((ks*48+nt)*64+lane)*8+e] = B[ks*32+(lane>>4)*8+e][nt*16+(lane&15)]
// nt = wc*12 + gate*3 + ti ; col j = wc*48 + ti*16 + (lane&15).
// ---------------------------------------------------------------------------
__global__ void prep_kernel(const float* __restrict__ wih, const float* __restrict__ whh,
                            const float* __restrict__ bih, const float* __restrict__ bhh,
                            unsigned short* __restrict__ Bpack, float* __restrict__ bias4,
                            uint4* __restrict__ mask16) {
  int gid = blockIdx.x * 256 + threadIdx.x;
  if (gid < 688) {
    int which = gid / 172, j = gid % 172;
    float v;
    if (which == 0)      v = bih[j]       + bhh[j];
    else if (which == 1) v = bih[172 + j] + bhh[172 + j];
    else if (which == 2) v = bih[344 + j];
    else                 v = bhh[344 + j];
    bias4[gid] = v;
  }
  if (gid < N_NODES / 16) mask16[gid] = make_uint4(0, 0, 0, 0);
  if (gid >= BPACK_USHORTS) return;
  int e  = gid & 7;
  int l  = (gid >> 3) & 63;
  int nt = (gid >> 9) % NTILES;
  int ks = gid / KSLICE;
  int k  = ks * 32 + ((l >> 4) << 3) + e;
  int c  = l & 15;
  int w  = nt / 12, tl = nt % 12;
  int gate = tl / 3, ti = tl % 3;
  int j = w * 48 + ti * 16 + c;
  float v = 0.f;
  if (j < D) {
    if (gate == 0) {
      if (k < D)        v = wih[j * D + k];
      else if (k < 2*D) v = whh[j * D + (k - D)];
    } else if (gate == 1) {
      if (k < D)        v = wih[(D + j) * D + k];
      else if (k < 2*D) v = whh[(D + j) * D + (k - D)];
    } else if (gate == 2) {
      if (k < D)        v = wih[(2*D + j) * D + k];
    } else {
      if (k >= D && k < 2*D) v = whh[(2*D + j) * D + (k - D)];
    }
  }
  Bpack[gid] = f2bf(v);
}

__global__ void mask_set_kernel(const int* __restrict__ ids, unsigned char* __restrict__ mask) {
  int i = blockIdx.x * 256 + threadIdx.x;
  if (i < N_UPD) mask[ids[i]] = 1;
}

// Full copy (fallback)
__global__ void copy_kernel(const float4* __restrict__ mem4, const float4* __restrict__ lu4,
                            float4* __restrict__ out4, float4* __restrict__ outlu4) {
  const long NL4 = N_NODES / 4;
  long stride = (long)gridDim.x * blockDim.x;
  for (long i = (long)blockIdx.x * blockDim.x + threadIdx.x; i < NM4 + NL4; i += stride) {
    if (i < NM4) out4[i] = mem4[i];
    else         outlu4[i - NM4] = lu4[i - NM4];
  }
}

// Masked copy: skip rows the GRU kernel writes. ~6.2 TB/s measured.
__global__ __launch_bounds__(256)
void copy_masked_kernel(const float4* __restrict__ mem4, const float* __restrict__ lu,
                        const unsigned char* __restrict__ mask,
                        float4* __restrict__ out4, float* __restrict__ outlu) {
  const unsigned stride = gridDim.x * 256;
  for (unsigned i = blockIdx.x * 256 + threadIdx.x; i < NM4; i += stride) {
    unsigned row = i / 43u;
    if (!mask[row]) out4[i] = mem4[i];
  }
  for (unsigned j = blockIdx.x * 256 + threadIdx.x; j < N_NODES; j += stride) {
    if (!mask[j]) outlu[j] = lu[j];
  }
}

// ---------------------------------------------------------------------------
// GRU v2: 64 rows/block, 8 waves = 2 m-groups x 4 col-groups.
// ti-loop (3 passes) keeps only 8 live accumulators (32 AGPR) -> high
// occupancy (target 4-5 waves/SIMD, 2 blocks/CU). B read from L2 (L3-hot,
// 0.5MB), loads batched per-ks before the MFMAs, unroll-2 pipelining,
// NO barriers in the K-loop.
// ---------------------------------------------------------------------------
__global__ __launch_bounds__(512, 4)
void gru64_kernel(const float* __restrict__ memory, const float* __restrict__ msgs,
                  const int* __restrict__ ids, const float* __restrict__ ts,
                  const unsigned short* __restrict__ Bpack, const float* __restrict__ bias4,
                  float* __restrict__ out_mem, float* __restrict__ out_lu) {
  __shared__ unsigned short At[BM * LDA];   // 46080 B
  const int tid  = threadIdx.x;
  const int m0   = blockIdx.x * BM;
  const int wave = tid >> 6, lane = tid & 63;
  const int g = lane >> 4, c = lane & 15;
  const int wm = wave >> 2, wc = wave & 3;

  // ---- A staging: 64 rows x (43 x-float4 + 43 h-float4) -> bf16 LDS ----
  const float4* x4 = (const float4*)msgs + (size_t)m0 * 43;
  float4 xv[6], hv[6];
  #pragma unroll
  for (int i = 0; i < 6; ++i) {
    int s = tid + i * 512;
    if (i < 5 || s < 2752) xv[i] = x4[s];
  }
  #pragma unroll
  for (int i = 0; i < 6; ++i) {
    int s = tid + i * 512;
    if (i < 5 || s < 2752) {
      int row = s / 43, seg = s - row * 43;
      hv[i] = ((const float4*)(memory + (size_t)ids[m0 + row] * D))[seg];
    }
  }
  #pragma unroll
  for (int i = 0; i < 6; ++i) {
    int s = tid + i * 512;
    if (i < 5 || s < 2752) {
      int row = s / 43, seg = s - row * 43;
      *(ushort4*)&At[row * LDA + seg * 4]       = f2bf4(xv[i]);
      *(ushort4*)&At[row * LDA + 172 + seg * 4] = f2bf4(hv[i]);
    }
  }
  if (tid < BM) {   // zero-pad k=344..351 (k=352..359 never read) + lu scatter
    *(uint4*)&At[tid * LDA + 344] = make_uint4(0, 0, 0, 0);
    out_lu[ids[m0 + tid]] = ts[m0 + tid];
  }
  __syncthreads();

  const int ar0 = (wm * 32 + c) * LDA;
  const int ar1 = ar0 + 16 * LDA;
  const short8* Bp = (const short8*)Bpack;

  #pragma unroll 1
  for (int ti = 0; ti < 3; ++ti) {
    if (wc == 3 && ti == 2) continue;   // j = 176..191: all padding
    // fragment base for (ks=0, gate=0, this ti): gate stride 192, ks stride 3072
    const short8* bp = Bp + (size_t)((wc * 12 + ti) * 64 + lane);

    f32x4 Cr0={0,0,0,0}, Cr1={0,0,0,0};  // gate r, m-tile 0/1
    f32x4 Cz0={0,0,0,0}, Cz1={0,0,0,0};
    f32x4 Ci0={0,0,0,0}, Ci1={0,0,0,0};
    f32x4 Ch0={0,0,0,0}, Ch1={0,0,0,0};

    #pragma unroll 2
    for (int ks = 0; ks < KSTEPS; ++ks) {
      // batch the 4 B-fragment loads first (independent, pipeline across unroll)
      const short8* bk = bp + ks * 3072;
      short8 br = bk[0];
      short8 bz = bk[192];
      short8 bi = bk[384];
      short8 bh = bk[576];
      short8 a0 = *(const short8*)&At[ar0 + ks * 32 + g * 8];
      short8 a1 = *(const short8*)&At[ar1 + ks * 32 + g * 8];
      Cr0 = __builtin_amdgcn_mfma_f32_16x16x32_bf16(a0, br, Cr0, 0, 0, 0);
      Cr1 = __builtin_amdgcn_mfma_f32_16x16x32_bf16(a1, br, Cr1, 0, 0, 0);
      Cz0 = __builtin_amdgcn_mfma_f32_16x16x32_bf16(a0, bz, Cz0, 0, 0, 0);
      Cz1 = __builtin_amdgcn_mfma_f32_16x16x32_bf16(a1, bz, Cz1, 0, 0, 0);
      Ci0 = __builtin_amdgcn_mfma_f32_16x16x32_bf16(a0, bi, Ci0, 0, 0, 0);
      Ci1 = __builtin_amdgcn_mfma_f32_16x16x32_bf16(a1, bi, Ci1, 0, 0, 0);
      Ch0 = __builtin_amdgcn_mfma_f32_16x16x32_bf16(a0, bh, Ch0, 0, 0, 0);
      Ch1 = __builtin_amdgcn_mfma_f32_16x16x32_bf16(a1, bh, Ch1, 0, 0, 0);
    }

    const int j = wc * 48 + ti * 16 + c;
    if (j < D) {
      const float b_r = bias4[j];
      const float b_z = bias4[172 + j];
      const float b_i = bias4[344 + j];
      const float b_h = bias4[516 + j];
      #pragma unroll
      for (int r = 0; r < 4; ++r) {
        {
          const int row_local = wm * 32 + g * 4 + r;
          float* orow = out_mem + (size_t)ids[m0 + row_local] * D;
          float ho = bf2f(At[row_local * LDA + 172 + j]);
          float rr = 1.f / (1.f + __expf(-(Cr0[r] + b_r)));
          float zz = 1.f / (1.f + __expf(-(Cz0[r] + b_z)));
          float e2 = __expf(2.f * (Ci0[r] + b_i + rr * (Ch0[r] + b_h)));
          float nn = 1.f - 2.f / (e2 + 1.f);
          orow[j] = nn + zz * (ho - nn);
        }
        {
          const int row_local = wm * 32 + 16 + g * 4 + r;
          float* orow = out_mem + (size_t)ids[m0 + row_local] * D;
          float ho = bf2f(At[row_local * LDA + 172 + j]);
          float rr = 1.f / (1.f + __expf(-(Cr1[r] + b_r)));
          float zz = 1.f / (1.f + __expf(-(Cz1[r] + b_z)));
          float e2 = __expf(2.f * (Ci1[r] + b_i + rr * (Ch1[r] + b_h)));
          float nn = 1.f - 2.f / (e2 + 1.f);
          orow[j] = nn + zz * (ho - nn);
        }
      }
    }
  }
}

extern "C" void kernel_launch(void* const* d_in, const int* in_sizes, int n_in,
                              void* d_out, int out_size, void* d_ws, size_t ws_size,
                              hipStream_t stream) {
  const float* memory      = (const float*)d_in[0];
  const float* last_update = (const float*)d_in[1];
  const int*   ids         = (const int*)  d_in[2];
  const float* msgs        = (const float*)d_in[3];
  const float* ts          = (const float*)d_in[4];
  const float* wih         = (const float*)d_in[5];
  const float* whh         = (const float*)d_in[6];
  const float* bih         = (const float*)d_in[7];
  const float* bhh         = (const float*)d_in[8];

  float* out_mem = (float*)d_out;
  float* out_lu  = out_mem + (size_t)N_NODES * D;

  unsigned short* Bpack = (unsigned short*)d_ws;
  float* bias4 = (float*)((char*)d_ws + BIAS_OFF);
  unsigned char* mask = (unsigned char*)d_ws + MASK_OFF;

  prep_kernel<<<BPACK_USHORTS / 256, 256, 0, stream>>>(wih, whh, bih, bhh, Bpack, bias4,
                                                       (uint4*)mask);
  if (ws_size >= WS_NEED) {
    mask_set_kernel<<<(N_UPD + 255) / 256, 256, 0, stream>>>(ids, mask);
    copy_masked_kernel<<<2048, 256, 0, stream>>>((const float4*)memory, last_update, mask,
                                                 (float4*)out_mem, out_lu);
  } else {
    copy_kernel<<<4096, 256, 0, stream>>>((const float4*)memory, (const float4*)last_update,
                                          (float4*)out_mem, (float4*)out_lu);
  }
  gru64_kernel<<<GRU_BLOCKS, 512, 0, stream>>>(memory, msgs, ids, ts, Bpack, bias4,
                                               out_mem, out_lu);
}